// Round 5
// baseline (237.552 us; speedup 1.0000x reference)
//
#include <hip/hip_runtime.h>
#include <hip/hip_bf16.h>
#include <math.h>

#define NH 8
#define NP 4
#define DD 64
#define DM 512

typedef unsigned short u16;
typedef unsigned int u32;

using frag_ab = __attribute__((ext_vector_type(8))) short;  // 8 bf16 (4 VGPRs)
using f32x4   = __attribute__((ext_vector_type(4))) float;  // 4 fp32 acc

__device__ __forceinline__ u16 f2b(float f) {               // fp32 -> bf16 (RNE)
    u32 u = __float_as_uint(f);
    u32 r = (u + 0x7FFFu + ((u >> 16) & 1u)) >> 16;
    return (u16)r;
}
__device__ __forceinline__ u32 pk2(float x, float y) {      // 2xf32 -> packed bf16x2 (RNE)
    float2 t; t.x = x; t.y = y;
    __hip_bfloat162 h = __float22bfloat162_rn(t);
    return *(u32*)&h;
}

#define GLOBAL_AS __attribute__((address_space(1)))
#define LDS_AS    __attribute__((address_space(3)))
__device__ __forceinline__ void async_copy16(void* lds, const void* g) {
    __builtin_amdgcn_global_load_lds((const GLOBAL_AS u32*)g, (LDS_AS u32*)lds, 16, 0, 0);
}

// counted-vmcnt barrier (T4): per step each wave issues 6 VMEM ops
// (2 gload_lds for A + 4 reg-loads for B).  vmcnt(6) retires exactly the
// previous tile's 6; the just-issued prefetch stays in flight.
#define VMW6_BARRIER() do {                                   \
    asm volatile("s_waitcnt vmcnt(6)" ::: "memory");          \
    __builtin_amdgcn_s_barrier();                             \
    __builtin_amdgcn_sched_barrier(0); } while (0)
#define VMW0_BARRIER() do {                                   \
    asm volatile("s_waitcnt vmcnt(0)" ::: "memory");          \
    __builtin_amdgcn_s_barrier();                             \
    __builtin_amdgcn_sched_barrier(0); } while (0)

// A-fragment ds_read (T2-swizzled) + lgkm retire barrier + MFMA vs reg-B.
// R4 post-mortem: LDS read port was the subscribed pipe (8 b128/wave/step);
// B now lives in registers (weights are L2-resident), halving ds_reads.
__device__ __forceinline__ void compute_afb(
    const u16* __restrict__ sa, int wrow, int lr, int kgs,
    const frag_ab (&bfr)[4], f32x4 (&acc)[4][4])
{
    frag_ab af[4];
#pragma unroll
    for (int i = 0; i < 4; ++i)
        af[i] = *(const frag_ab*)&sa[(wrow + i * 16 + lr) * 32 + kgs];
    asm volatile("s_waitcnt lgkmcnt(0)" ::: "memory");
    __builtin_amdgcn_s_barrier();                 // A-buffer reads retired ->
    __builtin_amdgcn_sched_barrier(0);            // safe to overwrite next step
#pragma unroll
    for (int i = 0; i < 4; ++i)
#pragma unroll
        for (int j = 0; j < 4; ++j)
            acc[i][j] = __builtin_amdgcn_mfma_f32_16x16x32_bf16(
                af[i], bfr[j], acc[i][j], 0, 0, 0);
}

// ---------------------------------------------------------------------------
// Merged projection GEMM.  BM=BN=128, BK=32, 256 threads (4 waves),
// wave tile 64x64 (acc[4][4]).  A: bf16 via global_load_lds into a
// double-buffered, T2-swizzled LDS tile.  B: direct global->register
// double-buffer (no LDS) — weights are small and L2-resident.
// Counted-vmcnt pipeline: never drain vmcnt to 0 in the main loop.
//   blockIdx.y < 5 : C = q_bf @ Wcat1^T + bcat1 (N=576; cols<512 -> q_ws bf16,
//                    512<=cols<576 -> offlog f32; frags >=576 skipped)
//   blockIdx.y >= 5: C = kv_bf @ Wcat2^T + bcat2 (N=1024 -> kv_ws bf16)
// ---------------------------------------------------------------------------
__global__ __launch_bounds__(256) void proj_gemm(
    const u16* __restrict__ q_bf, const u16* __restrict__ kv_bf,
    const u16* __restrict__ Wcat1, const u16* __restrict__ Wcat2,
    const float* __restrict__ bcat1, const float* __restrict__ bcat2,
    u16* __restrict__ q_ws, float* __restrict__ offlog,
    u16* __restrict__ kv_ws)
{
    constexpr int BM = 128, BK = 32;
    __shared__ u16 sA0[BM * BK], sA1[BM * BK];

    const int tid  = threadIdx.x;
    const int wave = tid >> 6;
    const int lane = tid & 63;
    const int m0 = blockIdx.x * BM;
    const bool is_q = blockIdx.y < 5;
    const int n0 = (is_q ? blockIdx.y : blockIdx.y - 5) * BM;
    const int Ncur = is_q ? 576 : 1024;
    const u16* __restrict__ A    = is_q ? q_bf : kv_bf;
    const u16* __restrict__ Wt   = is_q ? Wcat1 : Wcat2;
    const float* __restrict__ bias = is_q ? bcat1 : bcat2;

    const int wrow = 64 * (wave >> 1);
    const int wcol = 64 * (wave & 1);

    f32x4 acc[4][4] = {};
    const int lr = lane & 15;
    const int kg = lane >> 4;
    // T2 swizzle on the A path only (read slot / staging source slot)
    const int kgs = ((kg ^ ((lr >> 1) & 3)) << 3);
    const int sgo = (((lane & 3) ^ ((lane >> 3) & 3)) << 3);

    // hoist bias loads (oldest vm ops retire before the vmcnt(6) pipeline).
    float bv4[4];
#pragma unroll
    for (int j = 0; j < 4; ++j)
        bv4[j] = bias[n0 + wcol + j * 16 + lr];

    // A staging addresses (invariant except k0); source slot swizzled
    const int cA = wave * 64 + lane;            // first half chunk id
    const size_t arow0 = (size_t)(m0 + (cA >> 2)) * DM + sgo;
    const int cA2 = 256 + wave * 64 + lane;     // second half chunk id
    const size_t arow1 = (size_t)(m0 + (cA2 >> 2)) * DM + sgo;
    const int ldsA0 = wave * 512, ldsA1 = 2048 + wave * 512;

    // B register-load base: same 16B the old LDS path delivered (no swizzle)
    const size_t bbase = (size_t)(n0 + wcol + lr) * DM + kg * 8;

    auto stageA = [&](u16* sa, int k0) {         // 2 gload_lds per thread
        async_copy16(&sa[ldsA0], A + arow0 + k0);
        async_copy16(&sa[ldsA1], A + arow1 + k0);
    };
    auto loadB = [&](frag_ab (&b)[4], int k0) {  // 4 reg loads per thread
#pragma unroll
        for (int j = 0; j < 4; ++j)
            b[j] = *(const frag_ab*)(Wt + bbase + (size_t)j * 16 * DM + k0);
    };

    frag_ab b0[4], b1[4];
    stageA(sA0, 0);                              // prologue: tile 0 in flight
    loadB(b0, 0);

    for (int ktt = 0; ktt < 8; ++ktt) {
        // ---- even tile 2ktt (sA0/b0); prefetch 2ktt+1 -> sA1/b1 ----
        stageA(sA1, (2 * ktt + 1) << 5);
        loadB(b1, (2 * ktt + 1) << 5);
        VMW6_BARRIER();                          // tile 2ktt (A+B) complete
        compute_afb(sA0, wrow, lr, kgs, b0, acc);
        // ---- odd tile 2ktt+1 (sA1/b1); prefetch 2ktt+2 -> sA0/b0 ----
        if (ktt < 7) {
            stageA(sA0, (2 * ktt + 2) << 5);
            loadB(b0, (2 * ktt + 2) << 5);
            VMW6_BARRIER();
        } else {
            VMW0_BARRIER();                      // epilogue drain (last tile)
        }
        compute_afb(sA1, wrow, lr, kgs, b1, acc);
    }

    const int crow0 = (lane >> 4) * 4;
#pragma unroll
    for (int i = 0; i < 4; ++i) {
#pragma unroll
        for (int j = 0; j < 4; ++j) {
            const int colbase = n0 + wcol + j * 16;
            if (colbase >= Ncur) continue;        // wave-uniform tail skip
            const int col = colbase + lr;
            const float bv = bv4[j];
#pragma unroll
            for (int r = 0; r < 4; ++r) {
                const int row = m0 + wrow + i * 16 + crow0 + r;
                const float val = acc[i][j][r] + bv;
                if (!is_q)
                    kv_ws[(size_t)row * 1024 + col] = f2b(val);
                else if (colbase < 512)
                    q_ws[(size_t)row * 512 + col] = f2b(val);
                else
                    offlog[(size_t)row * 64 + (col - 512)] = val;
            }
        }
    }
}

// ---------------------------------------------------------------------------
// Output GEMM: C(f32) = A(bf16, Mx512) @ Wob^T + bo.  Same structure:
// LDS-staged A (counted-vmcnt dbuf) + register-double-buffered B.
// ---------------------------------------------------------------------------
__global__ __launch_bounds__(256) void out_gemm(
    const u16* __restrict__ A, const u16* __restrict__ Wt,
    const float* __restrict__ bias, float* __restrict__ C)
{
    constexpr int BM = 128, BK = 32;
    __shared__ u16 sA0[BM * BK], sA1[BM * BK];

    const int tid  = threadIdx.x;
    const int wave = tid >> 6;
    const int lane = tid & 63;
    const int m0 = blockIdx.x * BM;
    const int n0 = blockIdx.y * BM;

    const int wrow = 64 * (wave >> 1);
    const int wcol = 64 * (wave & 1);

    f32x4 acc[4][4] = {};
    const int lr = lane & 15;
    const int kg = lane >> 4;
    const int kgs = ((kg ^ ((lr >> 1) & 3)) << 3);
    const int sgo = (((lane & 3) ^ ((lane >> 3) & 3)) << 3);

    float bv4[4];
#pragma unroll
    for (int j = 0; j < 4; ++j)
        bv4[j] = bias[n0 + wcol + j * 16 + lr];  // col <= 511, in-bounds

    const int cA = wave * 64 + lane;
    const size_t arow0 = (size_t)(m0 + (cA >> 2)) * DM + sgo;
    const int cA2 = 256 + wave * 64 + lane;
    const size_t arow1 = (size_t)(m0 + (cA2 >> 2)) * DM + sgo;
    const int ldsA0 = wave * 512, ldsA1 = 2048 + wave * 512;

    const size_t bbase = (size_t)(n0 + wcol + lr) * DM + kg * 8;

    auto stageA = [&](u16* sa, int k0) {
        async_copy16(&sa[ldsA0], A + arow0 + k0);
        async_copy16(&sa[ldsA1], A + arow1 + k0);
    };
    auto loadB = [&](frag_ab (&b)[4], int k0) {
#pragma unroll
        for (int j = 0; j < 4; ++j)
            b[j] = *(const frag_ab*)(Wt + bbase + (size_t)j * 16 * DM + k0);
    };

    frag_ab b0[4], b1[4];
    stageA(sA0, 0);
    loadB(b0, 0);

    for (int ktt = 0; ktt < 8; ++ktt) {
        stageA(sA1, (2 * ktt + 1) << 5);
        loadB(b1, (2 * ktt + 1) << 5);
        VMW6_BARRIER();
        compute_afb(sA0, wrow, lr, kgs, b0, acc);
        if (ktt < 7) {
            stageA(sA0, (2 * ktt + 2) << 5);
            loadB(b0, (2 * ktt + 2) << 5);
            VMW6_BARRIER();
        } else {
            VMW0_BARRIER();
        }
        compute_afb(sA1, wrow, lr, kgs, b1, acc);
    }

    const int crow0 = (lane >> 4) * 4;
#pragma unroll
    for (int i = 0; i < 4; ++i) {
#pragma unroll
        for (int j = 0; j < 4; ++j) {
            const int col = n0 + wcol + j * 16 + lr;
            const float bv = bv4[j];
#pragma unroll
            for (int r = 0; r < 4; ++r) {
                const int row = m0 + wrow + i * 16 + crow0 + r;
                C[(size_t)row * 512 + col] = acc[i][j][r] + bv;
            }
        }
    }
}

// ---------------------------------------------------------------------------
// Weight/bias prep + input pre-cast (fp32 -> bf16), one launch.
//   Wcat1 = [Wq; Woff; Wa] (576x512, alloc 768)   bcat1 = [bq; boff; ba]
//   Wcat2 = [Wk; Wv]       (1024x512)             bcat2 = [bk; bv]
//   Wob   = Wo
//   q_bf / kv_bf = bf16 casts of q_in / kv_in (8 floats -> ushort8 per thread)
// ---------------------------------------------------------------------------
__global__ __launch_bounds__(256) void prep_weights(
    const float* __restrict__ Wq, const float* __restrict__ Woff,
    const float* __restrict__ Wa, const float* __restrict__ Wk,
    const float* __restrict__ Wv, const float* __restrict__ Wo,
    const float* __restrict__ bq, const float* __restrict__ boff,
    const float* __restrict__ ba, const float* __restrict__ bk,
    const float* __restrict__ bv,
    const float* __restrict__ q_in, const float* __restrict__ kv_in,
    u16* __restrict__ Wcat1, u16* __restrict__ Wcat2, u16* __restrict__ Wob,
    float* __restrict__ bcat1, float* __restrict__ bcat2,
    u16* __restrict__ q_bf, u16* __restrict__ kv_bf, int n8)
{
    const int W4  = 65536;   // 512*512/4
    const int W4s = 4096;    // 32*512/4
    const int WEND = 4 * W4 + 2 * W4s;   // 270336
    const int BEND = WEND + 2048;        // bias section (padded)
    int tid = blockIdx.x * 256 + threadIdx.x;
    if (tid < WEND) {
        const float* src; u16* dst; int off;
        int t = tid;
        if (t < W4)                    { src = Wq;    dst = Wcat1;           off = t; }
        else if ((t -= W4) < W4s)      { src = Woff;  dst = Wcat1 + 262144;  off = t; }
        else if ((t -= W4s) < W4s)     { src = Wa;    dst = Wcat1 + 278528;  off = t; }
        else if ((t -= W4s) < W4)      { src = Wk;    dst = Wcat2;           off = t; }
        else if ((t -= W4) < W4)       { src = Wv;    dst = Wcat2 + 262144;  off = t; }
        else                           { src = Wo;    dst = Wob;             off = t - W4; }
        float4 v = ((const float4*)src)[off];
        ushort4 o;
        o.x = f2b(v.x); o.y = f2b(v.y); o.z = f2b(v.z); o.w = f2b(v.w);
        ((ushort4*)dst)[off] = o;
    } else if (tid < BEND) {
        int j = tid - WEND;
        if (j < 576) {
            bcat1[j] = (j < 512) ? bq[j] : (j < 544 ? boff[j - 512] : ba[j - 544]);
        } else if (j < 1600) {
            int j2 = j - 576;
            bcat2[j2] = (j2 < 512) ? bk[j2] : bv[j2 - 512];
        }
    } else {
        int t = tid - BEND;              // 0 .. 2*n8-1, each handles 8 floats
        if (t < 2 * n8) {
            const float* src; u16* dst; int off;
            if (t < n8) { src = q_in;  dst = q_bf;  off = t; }
            else        { src = kv_in; dst = kv_bf; off = t - n8; }
            float4 a = ((const float4*)src)[off * 2];
            float4 b = ((const float4*)src)[off * 2 + 1];
            uint4 w;
            w.x = pk2(a.x, a.y); w.y = pk2(a.z, a.w);
            w.z = pk2(b.x, b.y); w.w = pk2(b.z, b.w);
            ((uint4*)dst)[off] = w;
        }
    }
}

// ---------------------------------------------------------------------------
// Banded deformable attention. One wave per (b, h, 16-query block).
// k|v fused buffer: row stride 1024, k at cols 0..511, v at 512..1023.
// ---------------------------------------------------------------------------
__global__ __launch_bounds__(256) void deform_attn_band(
    const u16* __restrict__ q, const u16* __restrict__ kv,
    const float* __restrict__ offlog, u16* __restrict__ out, int B, int L)
{
    __shared__ u16  sVt[4][64 * 40];
    __shared__ float sS[4][16 * 36];
    __shared__ float sW[4][16 * 36];

    const int wave = threadIdx.x >> 6;
    const int lane = threadIdx.x & 63;
    const int gw = blockIdx.x * 4 + wave;     // over B*NH*(L/16)
    const int nlb = L >> 4;
    const int lblk = gw % nlb;
    const int bh = gw / nlb;
    const int h = bh % NH;
    const int b = bh / NH;
    const int l0 = lblk << 4;

    u16*  __restrict__ vt = sVt[wave];
    float* __restrict__ Ss = sS[wave];
    float* __restrict__ Ws = sW[wave];

    const size_t brow = (size_t)b * L;
    const int headoff = h * DD;

    const int l_loc = lane >> 2, p = lane & 3;
    const size_t obase = (brow + l0 + l_loc) * 64 + h * 4 + p;
    const float offv  = offlog[obase];
    const float logit = offlog[obase + 32];

    const int fr = lane & 15, kg = lane >> 4;

    const u16* qrow = q + (brow + l0 + fr) * DM + headoff;
    frag_ab qf0 = *(const frag_ab*)(qrow + kg * 8);
    frag_ab qf1 = *(const frag_ab*)(qrow + kg * 8 + 32);

    frag_ab kf[2][2];
#pragma unroll
    for (int jf = 0; jf < 2; ++jf) {
        int rr = l0 - 8 + jf * 16 + fr;
        rr = min(max(rr, 0), L - 1);
        const u16* krow = kv + (brow + rr) * 1024 + headoff;
        kf[jf][0] = *(const frag_ab*)(krow + kg * 8);
        kf[jf][1] = *(const frag_ab*)(krow + kg * 8 + 32);
    }

    const int vr = lane & 31, vd0 = (lane >> 5) * 32;
    int vrr = min(max(l0 - 8 + vr, 0), L - 1);
    const u16* vrow = kv + (brow + vrr) * 1024 + 512 + headoff + vd0;
    frag_ab vl[4];
#pragma unroll
    for (int i = 0; i < 4; ++i)
        vl[i] = *(const frag_ab*)(vrow + i * 8);

    f32x4 accS[2] = {};
#pragma unroll
    for (int jf = 0; jf < 2; ++jf) {
        accS[jf] = __builtin_amdgcn_mfma_f32_16x16x32_bf16(qf0, kf[jf][0], accS[jf], 0, 0, 0);
        accS[jf] = __builtin_amdgcn_mfma_f32_16x16x32_bf16(qf1, kf[jf][1], accS[jf], 0, 0, 0);
    }

#pragma unroll
    for (int i = 0; i < 4; ++i)
#pragma unroll
        for (int j = 0; j < 8; ++j)
            vt[(vd0 + i * 8 + j) * 40 + vr] = (u16)vl[i][j];

#pragma unroll
    for (int jf = 0; jf < 2; ++jf)
#pragma unroll
        for (int r = 0; r < 4; ++r)
            Ss[(kg * 4 + r) * 36 + jf * 16 + fr] = accS[jf][r];

#pragma unroll
    for (int i = 0; i < 9; ++i)
        Ws[lane + 64 * i] = 0.f;

    __syncthreads();

    float pos = fminf(fmaxf((float)(l0 + l_loc) + offv, 0.f), (float)(L - 1));
    float ff = floorf(pos);
    int i0 = (int)ff;
    float fw = pos - ff;
    int c0 = i0 - (l0 - 8);
    c0 = min(max(c0, 0), 30);
    float S0 = Ss[l_loc * 36 + c0];
    float S1 = Ss[l_loc * 36 + c0 + 1];
    float t = (S0 + fw * (S1 - S0)) * 0.125f + logit;
    float m1 = fmaxf(t, __shfl_xor(t, 1));
    float mx = fmaxf(m1, __shfl_xor(m1, 2));
    float e = __expf(t - mx);
    float s1 = e + __shfl_xor(e, 1);
    float ssum = s1 + __shfl_xor(s1, 2);
    float wgt = e * __builtin_amdgcn_rcpf(ssum);
    atomicAdd(&Ws[l_loc * 36 + c0], (1.f - fw) * wgt);
    atomicAdd(&Ws[l_loc * 36 + c0 + 1], fw * wgt);

    __syncthreads();

    float4 w0 = *(const float4*)&Ws[fr * 36 + kg * 8];
    float4 w1 = *(const float4*)&Ws[fr * 36 + kg * 8 + 4];
    frag_ab wf;
    wf[0] = (short)f2b(w0.x); wf[1] = (short)f2b(w0.y);
    wf[2] = (short)f2b(w0.z); wf[3] = (short)f2b(w0.w);
    wf[4] = (short)f2b(w1.x); wf[5] = (short)f2b(w1.y);
    wf[6] = (short)f2b(w1.z); wf[7] = (short)f2b(w1.w);

#pragma unroll
    for (int md = 0; md < 4; ++md) {
        frag_ab af = *(const frag_ab*)&vt[(md * 16 + fr) * 40 + kg * 8];
        f32x4 o = {};
        o = __builtin_amdgcn_mfma_f32_16x16x32_bf16(af, wf, o, 0, 0, 0);
        ushort4 pk;
        pk.x = f2b(o[0]); pk.y = f2b(o[1]); pk.z = f2b(o[2]); pk.w = f2b(o[3]);
        *(ushort4*)&out[(brow + l0 + fr) * DM + headoff + md * 16 + kg * 4] = pk;
    }
}

// ---------------------------------------------------------------------------
extern "C" void kernel_launch(void* const* d_in, const int* in_sizes, int n_in,
                              void* d_out, int out_size, void* d_ws, size_t ws_size,
                              hipStream_t stream) {
    const float* q_in  = (const float*)d_in[0];
    const float* kv_in = (const float*)d_in[1];
    const float* Wq = (const float*)d_in[2];  const float* bq = (const float*)d_in[3];
    const float* Wk = (const float*)d_in[4];  const float* bk = (const float*)d_in[5];
    const float* Wv = (const float*)d_in[6];  const float* bv = (const float*)d_in[7];
    const float* Woff=(const float*)d_in[8];  const float* boff=(const float*)d_in[9];
    const float* Wa = (const float*)d_in[10]; const float* ba = (const float*)d_in[11];
    const float* Wo = (const float*)d_in[12]; const float* bo = (const float*)d_in[13];

    const int M = in_sizes[0] / DM;     // B*L = 16384
    const int L = 4096;
    const int B = M / L;

    char* p = (char*)d_ws;
    u16* attn_o = (u16*)p;               p += (size_t)M * DM * 2;     // attention output
    u16* Wcat1  = (u16*)p;               p += (size_t)768 * DM * 2;   // 640 used; pad for OOB staging
    u16* Wcat2  = (u16*)p;               p += (size_t)1024 * DM * 2;
    u16* Wob    = (u16*)p;               p += (size_t)DM * DM * 2;
    float* bcat1= (float*)p;             p += 640 * 4;
    float* bcat2= (float*)p;             p += 1024 * 4;
    u16* q_ws   = (u16*)p;               p += (size_t)M * DM * 2;
    u16* kv_ws  = (u16*)p;               p += (size_t)M * 1024 * 2;   // k|v fused
    float* offlog = (float*)p;           p += (size_t)M * 64 * 4;

    // bf16 input casts — alias dead regions (same-stream serialization):
    //   q_bf  lives prep->proj; attn_o is only written later by deform_attn_band
    //   kv_bf lives prep->proj; d_out is only written later by out_gemm (fully)
    u16* q_bf  = attn_o;
    u16* kv_bf = (u16*)d_out;

    const int n8 = M * DM / 8;          // 8 floats per cast thread
    const int prep_threads = 4 * 65536 + 2 * 4096 + 2048 + 2 * n8;
    hipLaunchKernelGGL(prep_weights, dim3((prep_threads + 255) / 256), dim3(256), 0, stream,
                       Wq, Woff, Wa, Wk, Wv, Wo, bq, boff, ba, bk, bv,
                       q_in, kv_in,
                       Wcat1, Wcat2, Wob, bcat1, bcat2, q_bf, kv_bf, n8);

    // merged projections (all-bf16): y<5 -> q/off/a, y>=5 -> k|v
    hipLaunchKernelGGL(proj_gemm, dim3(M / 128, 13), dim3(256), 0, stream,
                       q_bf, kv_bf, Wcat1, Wcat2, bcat1, bcat2,
                       q_ws, offlog, kv_ws);

    // banded attention: 1 wave per (b,h,16 queries)
    int nwaves = B * NH * (L / 16);
    hipLaunchKernelGGL(deform_attn_band, dim3(nwaves / 4), dim3(256), 0, stream,
                       q_ws, kv_ws, offlog, attn_o, B, L);

    // output projection -> fp32 d_out
    hipLaunchKernelGGL(out_gemm, dim3(M / 128, 4), dim3(256), 0, stream,
                       attn_o, Wob, bo, (float*)d_out);
}

// Round 6
// 202.609 us; speedup vs baseline: 1.1725x; 1.1725x over previous
//
#include <hip/hip_runtime.h>
#include <hip/hip_bf16.h>
#include <math.h>

#define NH 8
#define NP 4
#define DD 64
#define DM 512

typedef unsigned short u16;
typedef unsigned int u32;

using frag_ab = __attribute__((ext_vector_type(8))) short;  // 8 bf16 (4 VGPRs)
using f32x4   = __attribute__((ext_vector_type(4))) float;  // 4 fp32 acc

__device__ __forceinline__ u16 f2b(float f) {               // fp32 -> bf16 (RNE)
    u32 u = __float_as_uint(f);
    u32 r = (u + 0x7FFFu + ((u >> 16) & 1u)) >> 16;
    return (u16)r;
}
__device__ __forceinline__ u32 pk2(float x, float y) {      // 2xf32 -> packed bf16x2 (RNE)
    float2 t; t.x = x; t.y = y;
    __hip_bfloat162 h = __float22bfloat162_rn(t);
    return *(u32*)&h;
}

#define GLOBAL_AS __attribute__((address_space(1)))
#define LDS_AS    __attribute__((address_space(3)))
__device__ __forceinline__ void async_copy16(void* lds, const void* g) {
    __builtin_amdgcn_global_load_lds((const GLOBAL_AS u32*)g, (LDS_AS u32*)lds, 16, 0, 0);
}

// A-and-B fragment ds_read (T2-swizzled) + lgkm retire barrier + MFMA.
// (R5 post-mortem: reg-B was a strided gather — 64 cache lines per load —
// regressed 52->77 us.  Both operands stay LDS-staged via global_load_lds.)
__device__ __forceinline__ void compute_phase(
    const u16* __restrict__ sa, const u16* __restrict__ sb,
    int wrow, int wcol, int lr, int kgs, f32x4 (&acc)[4][4])
{
    frag_ab af[4], bfr[4];
#pragma unroll
    for (int i = 0; i < 4; ++i)
        af[i] = *(const frag_ab*)&sa[(wrow + i * 16 + lr) * 32 + kgs];
#pragma unroll
    for (int j = 0; j < 4; ++j)
        bfr[j] = *(const frag_ab*)&sb[(wcol + j * 16 + lr) * 32 + kgs];
    asm volatile("s_waitcnt lgkmcnt(0)" ::: "memory");
    __builtin_amdgcn_s_barrier();                 // buffer reads retired ->
    __builtin_amdgcn_sched_barrier(0);            // safe target for stage t+3
#pragma unroll
    for (int i = 0; i < 4; ++i)
#pragma unroll
        for (int j = 0; j < 4; ++j)
            acc[i][j] = __builtin_amdgcn_mfma_f32_16x16x32_bf16(
                af[i], bfr[j], acc[i][j], 0, 0, 0);
}

// ---------------------------------------------------------------------------
// Merged projection GEMM.  BM=BN=128, BK=32, 256 threads (4 waves),
// wave tile 64x64 (acc[4][4]).  BOTH operands bf16 via global_load_lds into
// TRIPLE-buffered, T2-swizzled LDS.  Depth-2 counted-vmcnt pipeline: tiles
// t+1 and t+2 stay in flight across the barrier (vmcnt(8)) so first-touch
// HBM latency (~900 cyc) is covered by two phases, not one.
//   blockIdx.y < 5 : C = q_bf @ Wcat1^T + bcat1 (N=576; cols<512 -> q_ws bf16,
//                    512<=cols<576 -> offlog f32; frags >=576 skipped)
//   blockIdx.y >= 5: C = kv_bf @ Wcat2^T + bcat2 (N=1024 -> kv_ws bf16)
// ---------------------------------------------------------------------------
__global__ __launch_bounds__(256) void proj_gemm(
    const u16* __restrict__ q_bf, const u16* __restrict__ kv_bf,
    const u16* __restrict__ Wcat1, const u16* __restrict__ Wcat2,
    const float* __restrict__ bcat1, const float* __restrict__ bcat2,
    u16* __restrict__ q_ws, float* __restrict__ offlog,
    u16* __restrict__ kv_ws)
{
    constexpr int BM = 128, BK = 32;
    __shared__ u16 sA[3][BM * BK];
    __shared__ u16 sB[3][BM * BK];

    const int tid  = threadIdx.x;
    const int wave = tid >> 6;
    const int lane = tid & 63;
    const int m0 = blockIdx.x * BM;
    const bool is_q = blockIdx.y < 5;
    const int n0 = (is_q ? blockIdx.y : blockIdx.y - 5) * BM;
    const int Ncur = is_q ? 576 : 1024;
    const u16* __restrict__ A    = is_q ? q_bf : kv_bf;
    const u16* __restrict__ Wt   = is_q ? Wcat1 : Wcat2;
    const float* __restrict__ bias = is_q ? bcat1 : bcat2;

    const int wrow = 64 * (wave >> 1);
    const int wcol = 64 * (wave & 1);

    f32x4 acc[4][4] = {};
    const int lr = lane & 15;
    const int kg = lane >> 4;
    // T2 swizzle (read slot / staging source slot) — bank conflicts stay 0
    const int kgs = ((kg ^ ((lr >> 1) & 3)) << 3);
    const int sgo = (((lane & 3) ^ ((lane >> 3) & 3)) << 3);

    // hoist bias loads: oldest vm ops, retired by the first counted wait
    float bv4[4];
#pragma unroll
    for (int j = 0; j < 4; ++j)
        bv4[j] = bias[n0 + wcol + j * 16 + lr];

    // staging addresses (invariant except k0); source slot swizzled
    const int cA = wave * 64 + lane;            // first half chunk id
    const size_t arow0 = (size_t)(m0 + (cA >> 2)) * DM + sgo;
    const int cA2 = 256 + wave * 64 + lane;     // second half chunk id
    const size_t arow1 = (size_t)(m0 + (cA2 >> 2)) * DM + sgo;
    const size_t brow0 = (size_t)(n0 + (cA >> 2)) * DM + sgo;
    const size_t brow1 = (size_t)(n0 + (cA2 >> 2)) * DM + sgo;
    const int ldsA0 = wave * 512, ldsA1 = 2048 + wave * 512;

    auto stage = [&](int bi, int k0) {           // 4 loads per thread per tile
        async_copy16(&sA[bi][ldsA0], A + arow0 + k0);
        async_copy16(&sA[bi][ldsA1], A + arow1 + k0);
        async_copy16(&sB[bi][ldsA0], Wt + brow0 + k0);
        async_copy16(&sB[bi][ldsA1], Wt + brow1 + k0);
    };

    stage(0, 0);                                 // prologue: tiles 0,1 in flight
    stage(1, 32);

#pragma unroll
    for (int t = 0; t < 16; ++t) {
        if (t + 2 < 16) {
            stage((t + 2) % 3, (t + 2) << 5);    // depth-2 prefetch
            asm volatile("s_waitcnt vmcnt(8)" ::: "memory");  // t done; t+1,t+2 fly
        } else if (t + 1 < 16) {
            asm volatile("s_waitcnt vmcnt(4)" ::: "memory");
        } else {
            asm volatile("s_waitcnt vmcnt(0)" ::: "memory");
        }
        __builtin_amdgcn_s_barrier();
        __builtin_amdgcn_sched_barrier(0);
        compute_phase(&sA[t % 3][0], &sB[t % 3][0], wrow, wcol, lr, kgs, acc);
    }

    const int crow0 = (lane >> 4) * 4;
#pragma unroll
    for (int i = 0; i < 4; ++i) {
#pragma unroll
        for (int j = 0; j < 4; ++j) {
            const int colbase = n0 + wcol + j * 16;
            if (colbase >= Ncur) continue;        // wave-uniform tail skip
            const int col = colbase + lr;
            const float bv = bv4[j];
#pragma unroll
            for (int r = 0; r < 4; ++r) {
                const int row = m0 + wrow + i * 16 + crow0 + r;
                const float val = acc[i][j][r] + bv;
                if (!is_q)
                    kv_ws[(size_t)row * 1024 + col] = f2b(val);
                else if (colbase < 512)
                    q_ws[(size_t)row * 512 + col] = f2b(val);
                else
                    offlog[(size_t)row * 64 + (col - 512)] = val;
            }
        }
    }
}

// ---------------------------------------------------------------------------
// Output GEMM: C(f32) = A(bf16, Mx512) @ Wob^T + bo.  Same triple-buffered
// depth-2 counted-vmcnt structure as proj_gemm.
// ---------------------------------------------------------------------------
__global__ __launch_bounds__(256) void out_gemm(
    const u16* __restrict__ A, const u16* __restrict__ Wt,
    const float* __restrict__ bias, float* __restrict__ C)
{
    constexpr int BM = 128, BK = 32;
    __shared__ u16 sA[3][BM * BK];
    __shared__ u16 sB[3][BM * BK];

    const int tid  = threadIdx.x;
    const int wave = tid >> 6;
    const int lane = tid & 63;
    const int m0 = blockIdx.x * BM;
    const int n0 = blockIdx.y * BM;

    const int wrow = 64 * (wave >> 1);
    const int wcol = 64 * (wave & 1);

    f32x4 acc[4][4] = {};
    const int lr = lane & 15;
    const int kg = lane >> 4;
    const int kgs = ((kg ^ ((lr >> 1) & 3)) << 3);
    const int sgo = (((lane & 3) ^ ((lane >> 3) & 3)) << 3);

    float bv4[4];
#pragma unroll
    for (int j = 0; j < 4; ++j)
        bv4[j] = bias[n0 + wcol + j * 16 + lr];  // col <= 511, in-bounds

    const int cA = wave * 64 + lane;
    const size_t arow0 = (size_t)(m0 + (cA >> 2)) * DM + sgo;
    const int cA2 = 256 + wave * 64 + lane;
    const size_t arow1 = (size_t)(m0 + (cA2 >> 2)) * DM + sgo;
    const size_t brow0 = (size_t)(n0 + (cA >> 2)) * DM + sgo;
    const size_t brow1 = (size_t)(n0 + (cA2 >> 2)) * DM + sgo;
    const int ldsA0 = wave * 512, ldsA1 = 2048 + wave * 512;

    auto stage = [&](int bi, int k0) {
        async_copy16(&sA[bi][ldsA0], A + arow0 + k0);
        async_copy16(&sA[bi][ldsA1], A + arow1 + k0);
        async_copy16(&sB[bi][ldsA0], Wt + brow0 + k0);
        async_copy16(&sB[bi][ldsA1], Wt + brow1 + k0);
    };

    stage(0, 0);
    stage(1, 32);

#pragma unroll
    for (int t = 0; t < 16; ++t) {
        if (t + 2 < 16) {
            stage((t + 2) % 3, (t + 2) << 5);
            asm volatile("s_waitcnt vmcnt(8)" ::: "memory");
        } else if (t + 1 < 16) {
            asm volatile("s_waitcnt vmcnt(4)" ::: "memory");
        } else {
            asm volatile("s_waitcnt vmcnt(0)" ::: "memory");
        }
        __builtin_amdgcn_s_barrier();
        __builtin_amdgcn_sched_barrier(0);
        compute_phase(&sA[t % 3][0], &sB[t % 3][0], wrow, wcol, lr, kgs, acc);
    }

    const int crow0 = (lane >> 4) * 4;
#pragma unroll
    for (int i = 0; i < 4; ++i) {
#pragma unroll
        for (int j = 0; j < 4; ++j) {
            const int col = n0 + wcol + j * 16 + lr;
            const float bv = bv4[j];
#pragma unroll
            for (int r = 0; r < 4; ++r) {
                const int row = m0 + wrow + i * 16 + crow0 + r;
                C[(size_t)row * 512 + col] = acc[i][j][r] + bv;
            }
        }
    }
}

// ---------------------------------------------------------------------------
// Weight/bias prep + input pre-cast (fp32 -> bf16), one launch.
//   Wcat1 = [Wq; Woff; Wa] (576x512, alloc 768)   bcat1 = [bq; boff; ba]
//   Wcat2 = [Wk; Wv]       (1024x512)             bcat2 = [bk; bv]
//   Wob   = Wo
//   q_bf / kv_bf = bf16 casts of q_in / kv_in (8 floats -> ushort8 per thread)
// ---------------------------------------------------------------------------
__global__ __launch_bounds__(256) void prep_weights(
    const float* __restrict__ Wq, const float* __restrict__ Woff,
    const float* __restrict__ Wa, const float* __restrict__ Wk,
    const float* __restrict__ Wv, const float* __restrict__ Wo,
    const float* __restrict__ bq, const float* __restrict__ boff,
    const float* __restrict__ ba, const float* __restrict__ bk,
    const float* __restrict__ bv,
    const float* __restrict__ q_in, const float* __restrict__ kv_in,
    u16* __restrict__ Wcat1, u16* __restrict__ Wcat2, u16* __restrict__ Wob,
    float* __restrict__ bcat1, float* __restrict__ bcat2,
    u16* __restrict__ q_bf, u16* __restrict__ kv_bf, int n8)
{
    const int W4  = 65536;   // 512*512/4
    const int W4s = 4096;    // 32*512/4
    const int WEND = 4 * W4 + 2 * W4s;   // 270336
    const int BEND = WEND + 2048;        // bias section (padded)
    int tid = blockIdx.x * 256 + threadIdx.x;
    if (tid < WEND) {
        const float* src; u16* dst; int off;
        int t = tid;
        if (t < W4)                    { src = Wq;    dst = Wcat1;           off = t; }
        else if ((t -= W4) < W4s)      { src = Woff;  dst = Wcat1 + 262144;  off = t; }
        else if ((t -= W4s) < W4s)     { src = Wa;    dst = Wcat1 + 278528;  off = t; }
        else if ((t -= W4s) < W4)      { src = Wk;    dst = Wcat2;           off = t; }
        else if ((t -= W4) < W4)       { src = Wv;    dst = Wcat2 + 262144;  off = t; }
        else                           { src = Wo;    dst = Wob;             off = t - W4; }
        float4 v = ((const float4*)src)[off];
        ushort4 o;
        o.x = f2b(v.x); o.y = f2b(v.y); o.z = f2b(v.z); o.w = f2b(v.w);
        ((ushort4*)dst)[off] = o;
    } else if (tid < BEND) {
        int j = tid - WEND;
        if (j < 576) {
            bcat1[j] = (j < 512) ? bq[j] : (j < 544 ? boff[j - 512] : ba[j - 544]);
        } else if (j < 1600) {
            int j2 = j - 576;
            bcat2[j2] = (j2 < 512) ? bk[j2] : bv[j2 - 512];
        }
    } else {
        int t = tid - BEND;              // 0 .. 2*n8-1, each handles 8 floats
        if (t < 2 * n8) {
            const float* src; u16* dst; int off;
            if (t < n8) { src = q_in;  dst = q_bf;  off = t; }
            else        { src = kv_in; dst = kv_bf; off = t - n8; }
            float4 a = ((const float4*)src)[off * 2];
            float4 b = ((const float4*)src)[off * 2 + 1];
            uint4 w;
            w.x = pk2(a.x, a.y); w.y = pk2(a.z, a.w);
            w.z = pk2(b.x, b.y); w.w = pk2(b.z, b.w);
            ((uint4*)dst)[off] = w;
        }
    }
}

// ---------------------------------------------------------------------------
// Banded deformable attention. One wave per (b, h, 16-query block).
// k|v fused buffer: row stride 1024, k at cols 0..511, v at 512..1023.
// The 4 waves of a block are fully LDS-independent (per-wave sVt/sS/sW
// slices), so block-wide __syncthreads is replaced by wave-local
// s_waitcnt lgkmcnt(0): a wave's own DS writes are complete before its
// subsequent reads; no cross-wave rendezvous.
// ---------------------------------------------------------------------------
#define WAVE_SYNC() do {                                      \
    asm volatile("s_waitcnt lgkmcnt(0)" ::: "memory");        \
    __builtin_amdgcn_sched_barrier(0); } while (0)

__global__ __launch_bounds__(256) void deform_attn_band(
    const u16* __restrict__ q, const u16* __restrict__ kv,
    const float* __restrict__ offlog, u16* __restrict__ out, int B, int L)
{
    __shared__ u16  sVt[4][64 * 40];
    __shared__ float sS[4][16 * 36];
    __shared__ float sW[4][16 * 36];

    const int wave = threadIdx.x >> 6;
    const int lane = threadIdx.x & 63;
    const int gw = blockIdx.x * 4 + wave;     // over B*NH*(L/16)
    const int nlb = L >> 4;
    const int lblk = gw % nlb;
    const int bh = gw / nlb;
    const int h = bh % NH;
    const int b = bh / NH;
    const int l0 = lblk << 4;

    u16*  __restrict__ vt = sVt[wave];
    float* __restrict__ Ss = sS[wave];
    float* __restrict__ Ws = sW[wave];

    const size_t brow = (size_t)b * L;
    const int headoff = h * DD;

    const int l_loc = lane >> 2, p = lane & 3;
    const size_t obase = (brow + l0 + l_loc) * 64 + h * 4 + p;
    const float offv  = offlog[obase];
    const float logit = offlog[obase + 32];

    const int fr = lane & 15, kg = lane >> 4;

    const u16* qrow = q + (brow + l0 + fr) * DM + headoff;
    frag_ab qf0 = *(const frag_ab*)(qrow + kg * 8);
    frag_ab qf1 = *(const frag_ab*)(qrow + kg * 8 + 32);

    frag_ab kf[2][2];
#pragma unroll
    for (int jf = 0; jf < 2; ++jf) {
        int rr = l0 - 8 + jf * 16 + fr;
        rr = min(max(rr, 0), L - 1);
        const u16* krow = kv + (brow + rr) * 1024 + headoff;
        kf[jf][0] = *(const frag_ab*)(krow + kg * 8);
        kf[jf][1] = *(const frag_ab*)(krow + kg * 8 + 32);
    }

    const int vr = lane & 31, vd0 = (lane >> 5) * 32;
    int vrr = min(max(l0 - 8 + vr, 0), L - 1);
    const u16* vrow = kv + (brow + vrr) * 1024 + 512 + headoff + vd0;
    frag_ab vl[4];
#pragma unroll
    for (int i = 0; i < 4; ++i)
        vl[i] = *(const frag_ab*)(vrow + i * 8);

    f32x4 accS[2] = {};
#pragma unroll
    for (int jf = 0; jf < 2; ++jf) {
        accS[jf] = __builtin_amdgcn_mfma_f32_16x16x32_bf16(qf0, kf[jf][0], accS[jf], 0, 0, 0);
        accS[jf] = __builtin_amdgcn_mfma_f32_16x16x32_bf16(qf1, kf[jf][1], accS[jf], 0, 0, 0);
    }

#pragma unroll
    for (int i = 0; i < 4; ++i)
#pragma unroll
        for (int j = 0; j < 8; ++j)
            vt[(vd0 + i * 8 + j) * 40 + vr] = (u16)vl[i][j];

#pragma unroll
    for (int jf = 0; jf < 2; ++jf)
#pragma unroll
        for (int r = 0; r < 4; ++r)
            Ss[(kg * 4 + r) * 36 + jf * 16 + fr] = accS[jf][r];

#pragma unroll
    for (int i = 0; i < 9; ++i)
        Ws[lane + 64 * i] = 0.f;

    WAVE_SYNC();

    float pos = fminf(fmaxf((float)(l0 + l_loc) + offv, 0.f), (float)(L - 1));
    float ff = floorf(pos);
    int i0 = (int)ff;
    float fw = pos - ff;
    int c0 = i0 - (l0 - 8);
    c0 = min(max(c0, 0), 30);
    float S0 = Ss[l_loc * 36 + c0];
    float S1 = Ss[l_loc * 36 + c0 + 1];
    float t = (S0 + fw * (S1 - S0)) * 0.125f + logit;
    float m1 = fmaxf(t, __shfl_xor(t, 1));
    float mx = fmaxf(m1, __shfl_xor(m1, 2));
    float e = __expf(t - mx);
    float s1 = e + __shfl_xor(e, 1);
    float ssum = s1 + __shfl_xor(s1, 2);
    float wgt = e * __builtin_amdgcn_rcpf(ssum);
    atomicAdd(&Ws[l_loc * 36 + c0], (1.f - fw) * wgt);
    atomicAdd(&Ws[l_loc * 36 + c0 + 1], fw * wgt);

    WAVE_SYNC();

    float4 w0 = *(const float4*)&Ws[fr * 36 + kg * 8];
    float4 w1 = *(const float4*)&Ws[fr * 36 + kg * 8 + 4];
    frag_ab wf;
    wf[0] = (short)f2b(w0.x); wf[1] = (short)f2b(w0.y);
    wf[2] = (short)f2b(w0.z); wf[3] = (short)f2b(w0.w);
    wf[4] = (short)f2b(w1.x); wf[5] = (short)f2b(w1.y);
    wf[6] = (short)f2b(w1.z); wf[7] = (short)f2b(w1.w);

#pragma unroll
    for (int md = 0; md < 4; ++md) {
        frag_ab af = *(const frag_ab*)&vt[(md * 16 + fr) * 40 + kg * 8];
        f32x4 o = {};
        o = __builtin_amdgcn_mfma_f32_16x16x32_bf16(af, wf, o, 0, 0, 0);
        ushort4 pk;
        pk.x = f2b(o[0]); pk.y = f2b(o[1]); pk.z = f2b(o[2]); pk.w = f2b(o[3]);
        *(ushort4*)&out[(brow + l0 + fr) * DM + headoff + md * 16 + kg * 4] = pk;
    }
}

// ---------------------------------------------------------------------------
extern "C" void kernel_launch(void* const* d_in, const int* in_sizes, int n_in,
                              void* d_out, int out_size, void* d_ws, size_t ws_size,
                              hipStream_t stream) {
    const float* q_in  = (const float*)d_in[0];
    const float* kv_in = (const float*)d_in[1];
    const float* Wq = (const float*)d_in[2];  const float* bq = (const float*)d_in[3];
    const float* Wk = (const float*)d_in[4];  const float* bk = (const float*)d_in[5];
    const float* Wv = (const float*)d_in[6];  const float* bv = (const float*)d_in[7];
    const float* Woff=(const float*)d_in[8];  const float* boff=(const float*)d_in[9];
    const float* Wa = (const float*)d_in[10]; const float* ba = (const float*)d_in[11];
    const float* Wo = (const float*)d_in[12]; const float* bo = (const float*)d_in[13];

    const int M = in_sizes[0] / DM;     // B*L = 16384
    const int L = 4096;
    const int B = M / L;

    char* p = (char*)d_ws;
    u16* attn_o = (u16*)p;               p += (size_t)M * DM * 2;     // attention output
    u16* Wcat1  = (u16*)p;               p += (size_t)768 * DM * 2;   // 640 used; pad for OOB staging
    u16* Wcat2  = (u16*)p;               p += (size_t)1024 * DM * 2;
    u16* Wob    = (u16*)p;               p += (size_t)DM * DM * 2;
    float* bcat1= (float*)p;             p += 640 * 4;
    float* bcat2= (float*)p;             p += 1024 * 4;
    u16* q_ws   = (u16*)p;               p += (size_t)M * DM * 2;
    u16* kv_ws  = (u16*)p;               p += (size_t)M * 1024 * 2;   // k|v fused
    float* offlog = (float*)p;           p += (size_t)M * 64 * 4;

    // bf16 input casts — alias dead regions (same-stream serialization):
    //   q_bf  lives prep->proj; attn_o is only written later by deform_attn_band
    //   kv_bf lives prep->proj; d_out is only written later by out_gemm (fully)
    u16* q_bf  = attn_o;
    u16* kv_bf = (u16*)d_out;

    const int n8 = M * DM / 8;          // 8 floats per cast thread
    const int prep_threads = 4 * 65536 + 2 * 4096 + 2048 + 2 * n8;
    hipLaunchKernelGGL(prep_weights, dim3((prep_threads + 255) / 256), dim3(256), 0, stream,
                       Wq, Woff, Wa, Wk, Wv, Wo, bq, boff, ba, bk, bv,
                       q_in, kv_in,
                       Wcat1, Wcat2, Wob, bcat1, bcat2, q_bf, kv_bf, n8);

    // merged projections (all-bf16 async staging): y<5 -> q/off/a, y>=5 -> k|v
    hipLaunchKernelGGL(proj_gemm, dim3(M / 128, 13), dim3(256), 0, stream,
                       q_bf, kv_bf, Wcat1, Wcat2, bcat1, bcat2,
                       q_ws, offlog, kv_ws);

    // banded attention: 1 wave per (b,h,16 queries)
    int nwaves = B * NH * (L / 16);
    hipLaunchKernelGGL(deform_attn_band, dim3(nwaves / 4), dim3(256), 0, stream,
                       q_ws, kv_ws, offlog, attn_o, B, L);

    // output projection -> fp32 d_out
    hipLaunchKernelGGL(out_gemm, dim3(M / 128, 4), dim3(256), 0, stream,
                       attn_o, Wob, bo, (float*)d_out);
}

// Round 8
// 200.954 us; speedup vs baseline: 1.1821x; 1.0082x over previous
//
#include <hip/hip_runtime.h>
#include <hip/hip_bf16.h>
#include <math.h>

#define NH 8
#define NP 4
#define DD 64
#define DM 512

typedef unsigned short u16;
typedef unsigned int u32;

using frag_ab = __attribute__((ext_vector_type(8))) short;  // 8 bf16 (4 VGPRs)
using f32x4   = __attribute__((ext_vector_type(4))) float;  // 4 fp32 acc

__device__ __forceinline__ u16 f2b(float f) {               // fp32 -> bf16 (RNE)
    u32 u = __float_as_uint(f);
    u32 r = (u + 0x7FFFu + ((u >> 16) & 1u)) >> 16;
    return (u16)r;
}
__device__ __forceinline__ u32 pk2(float x, float y) {      // 2xf32 -> packed bf16x2 (RNE)
    float2 t; t.x = x; t.y = y;
    __hip_bfloat162 h = __float22bfloat162_rn(t);
    return *(u32*)&h;
}

#define GLOBAL_AS __attribute__((address_space(1)))
#define LDS_AS    __attribute__((address_space(3)))
__device__ __forceinline__ void async_copy16(void* lds, const void* g) {
    __builtin_amdgcn_global_load_lds((const GLOBAL_AS u32*)g, (LDS_AS u32*)lds, 16, 0, 0);
}

// counted-vmcnt barrier (T4): per step each thread issues 2 gload_lds.
// vmcnt(2) retires exactly the previous tile's 2; the just-issued prefetch
// stays in flight (never drain to 0 in the main loop).
#define VMW2_BARRIER() do {                                   \
    asm volatile("s_waitcnt vmcnt(2)" ::: "memory");          \
    __builtin_amdgcn_s_barrier();                             \
    __builtin_amdgcn_sched_barrier(0); } while (0)
#define VMW0_BARRIER() do {                                   \
    asm volatile("s_waitcnt vmcnt(0)" ::: "memory");          \
    __builtin_amdgcn_s_barrier();                             \
    __builtin_amdgcn_sched_barrier(0); } while (0)

// 8-wave fragment read (T2-swizzled) + lgkm retire barrier + MFMA.
// R6 post-mortem: prefetch depth is saturated; the binding constraint was
// occupancy (24%, 2 blocks/CU of 4 waves).  8-wave blocks halve per-wave
// phase work and lift CU wave count ~3x at the same LDS footprint.
__device__ __forceinline__ void compute_phase8(
    const u16* __restrict__ sa, const u16* __restrict__ sb,
    int wrow, int wcol, int lr, int kgs, f32x4 (&acc)[4][2])
{
    frag_ab af[4], bfr[2];
#pragma unroll
    for (int i = 0; i < 4; ++i)
        af[i] = *(const frag_ab*)&sa[(wrow + i * 16 + lr) * 32 + kgs];
#pragma unroll
    for (int j = 0; j < 2; ++j)
        bfr[j] = *(const frag_ab*)&sb[(wcol + j * 16 + lr) * 32 + kgs];
    asm volatile("s_waitcnt lgkmcnt(0)" ::: "memory");
    __builtin_amdgcn_s_barrier();                 // buffer reads retired ->
    __builtin_amdgcn_sched_barrier(0);            // safe to overwrite next step
#pragma unroll
    for (int i = 0; i < 4; ++i)
#pragma unroll
        for (int j = 0; j < 2; ++j)
            acc[i][j] = __builtin_amdgcn_mfma_f32_16x16x32_bf16(
                af[i], bfr[j], acc[i][j], 0, 0, 0);
}

// ---------------------------------------------------------------------------
// Merged projection GEMM.  BM=BN=128, BK=32, **512 threads (8 waves)**,
// wave tile 64x32 (acc[4][2], waves in 2x4 grid).  BOTH operands bf16 via
// global_load_lds into double-buffered, T2-swizzled LDS (32 KB total).
// Depth-1 counted-vmcnt pipeline (vmcnt(2)); static buffers, unroll-by-2.
//   blockIdx.y < 5 : C = q_bf @ Wcat1^T + bcat1 (N=576; cols<512 -> q_ws bf16,
//                    512<=cols<576 -> offlog f32; frags >=576 skipped)
//   blockIdx.y >= 5: C = kv_bf @ Wcat2^T + bcat2 (N=1024 -> kv_ws bf16)
// ---------------------------------------------------------------------------
__global__ __launch_bounds__(512) void proj_gemm(
    const u16* __restrict__ q_bf, const u16* __restrict__ kv_bf,
    const u16* __restrict__ Wcat1, const u16* __restrict__ Wcat2,
    const float* __restrict__ bcat1, const float* __restrict__ bcat2,
    u16* __restrict__ q_ws, float* __restrict__ offlog,
    u16* __restrict__ kv_ws)
{
    constexpr int BM = 128, BK = 32;
    __shared__ u16 sA0[BM * BK], sA1[BM * BK];
    __shared__ u16 sB0[BM * BK], sB1[BM * BK];

    const int tid  = threadIdx.x;
    const int wave = tid >> 6;
    const int lane = tid & 63;
    const int m0 = blockIdx.x * BM;
    const bool is_q = blockIdx.y < 5;
    const int n0 = (is_q ? blockIdx.y : blockIdx.y - 5) * BM;
    const int Ncur = is_q ? 576 : 1024;
    const u16* __restrict__ A    = is_q ? q_bf : kv_bf;
    const u16* __restrict__ Wt   = is_q ? Wcat1 : Wcat2;
    const float* __restrict__ bias = is_q ? bcat1 : bcat2;

    const int wrow = 64 * (wave >> 2);            // 2 wave-rows of 64
    const int wcol = 32 * (wave & 3);             // 4 wave-cols of 32

    f32x4 acc[4][2] = {};
    const int lr = lane & 15;
    const int kg = lane >> 4;
    // T2 swizzle (proven R4): LDS slot s of row r holds global slot s^((r>>1)&3)
    const int kgs = ((kg ^ ((lr >> 1) & 3)) << 3);                 // read side
    const int sgo = (((tid & 3) ^ ((tid >> 3) & 3)) << 3);         // stage side

    // hoist bias loads: oldest vm ops, retired by the first vmcnt(2)
    float bv2[2];
#pragma unroll
    for (int j = 0; j < 2; ++j)
        bv2[j] = bias[n0 + wcol + j * 16 + lr];   // bcat1 has 640 floats: max 639

    // staging: chunk c = tid covers the full 128x32 tile (512 x 16B)
    const size_t arow = (size_t)(m0 + (tid >> 2)) * DM + sgo;
    const size_t brow = (size_t)(n0 + (tid >> 2)) * DM + sgo;
    const int ldsoff = tid * 8;                   // u16 units = tid*16 B

    auto stage = [&](u16* sa, u16* sb, int k0) {  // 2 loads per thread per tile
        async_copy16(&sa[ldsoff], A + arow + k0);
        async_copy16(&sb[ldsoff], Wt + brow + k0);
    };

    stage(sA0, sB0, 0);                           // prologue: tile 0 in flight

    for (int ktt = 0; ktt < 8; ++ktt) {
        // ---- even tile 2ktt (buf0); prefetch 2ktt+1 -> buf1 ----
        stage(sA1, sB1, (2 * ktt + 1) << 5);
        VMW2_BARRIER();                           // tile 2ktt complete
        compute_phase8(sA0, sB0, wrow, wcol, lr, kgs, acc);
        // ---- odd tile 2ktt+1 (buf1); prefetch 2ktt+2 -> buf0 ----
        if (ktt < 7) {
            stage(sA0, sB0, (2 * ktt + 2) << 5);
            VMW2_BARRIER();
        } else {
            VMW0_BARRIER();                       // epilogue drain (last tile)
        }
        compute_phase8(sA1, sB1, wrow, wcol, lr, kgs, acc);
    }

    const int crow0 = kg * 4;
#pragma unroll
    for (int i = 0; i < 4; ++i) {
#pragma unroll
        for (int j = 0; j < 2; ++j) {
            const int colbase = n0 + wcol + j * 16;
            if (colbase >= Ncur) continue;        // wave-uniform tail skip
            const int col = colbase + lr;
            const float bv = bv2[j];
#pragma unroll
            for (int r = 0; r < 4; ++r) {
                const int row = m0 + wrow + i * 16 + crow0 + r;
                const float val = acc[i][j][r] + bv;
                if (!is_q)
                    kv_ws[(size_t)row * 1024 + col] = f2b(val);
                else if (colbase < 512)
                    q_ws[(size_t)row * 512 + col] = f2b(val);
                else
                    offlog[(size_t)row * 64 + (col - 512)] = val;
            }
        }
    }
}

// ---------------------------------------------------------------------------
// Output GEMM: C(f32) = A(bf16, Mx512) @ Wob^T + bo.  Same 8-wave
// counted-vmcnt structure as proj_gemm.
// ---------------------------------------------------------------------------
__global__ __launch_bounds__(512) void out_gemm(
    const u16* __restrict__ A, const u16* __restrict__ Wt,
    const float* __restrict__ bias, float* __restrict__ C)
{
    constexpr int BM = 128, BK = 32;
    __shared__ u16 sA0[BM * BK], sA1[BM * BK];
    __shared__ u16 sB0[BM * BK], sB1[BM * BK];

    const int tid  = threadIdx.x;
    const int wave = tid >> 6;
    const int lane = tid & 63;
    const int m0 = blockIdx.x * BM;
    const int n0 = blockIdx.y * BM;

    const int wrow = 64 * (wave >> 2);
    const int wcol = 32 * (wave & 3);

    f32x4 acc[4][2] = {};
    const int lr = lane & 15;
    const int kg = lane >> 4;
    const int kgs = ((kg ^ ((lr >> 1) & 3)) << 3);
    const int sgo = (((tid & 3) ^ ((tid >> 3) & 3)) << 3);

    float bv2[2];
#pragma unroll
    for (int j = 0; j < 2; ++j)
        bv2[j] = bias[n0 + wcol + j * 16 + lr];   // col <= 511, in-bounds

    const size_t arow = (size_t)(m0 + (tid >> 2)) * DM + sgo;
    const size_t brow = (size_t)(n0 + (tid >> 2)) * DM + sgo;
    const int ldsoff = tid * 8;

    auto stage = [&](u16* sa, u16* sb, int k0) {
        async_copy16(&sa[ldsoff], A + arow + k0);
        async_copy16(&sb[ldsoff], Wt + brow + k0);
    };

    stage(sA0, sB0, 0);

    for (int ktt = 0; ktt < 8; ++ktt) {
        stage(sA1, sB1, (2 * ktt + 1) << 5);
        VMW2_BARRIER();
        compute_phase8(sA0, sB0, wrow, wcol, lr, kgs, acc);
        if (ktt < 7) {
            stage(sA0, sB0, (2 * ktt + 2) << 5);
            VMW2_BARRIER();
        } else {
            VMW0_BARRIER();
        }
        compute_phase8(sA1, sB1, wrow, wcol, lr, kgs, acc);
    }

    const int crow0 = kg * 4;
#pragma unroll
    for (int i = 0; i < 4; ++i) {
#pragma unroll
        for (int j = 0; j < 2; ++j) {
            const int col = n0 + wcol + j * 16 + lr;
            const float bv = bv2[j];
#pragma unroll
            for (int r = 0; r < 4; ++r) {
                const int row = m0 + wrow + i * 16 + crow0 + r;
                C[(size_t)row * 512 + col] = acc[i][j][r] + bv;
            }
        }
    }
}

// ---------------------------------------------------------------------------
// Weight/bias prep + input pre-cast (fp32 -> bf16), one launch.
//   Wcat1 = [Wq; Woff; Wa] (576x512, alloc 768)   bcat1 = [bq; boff; ba]
//   Wcat2 = [Wk; Wv]       (1024x512)             bcat2 = [bk; bv]
//   Wob   = Wo
//   q_bf / kv_bf = bf16 casts of q_in / kv_in (8 floats -> ushort8 per thread)
// ---------------------------------------------------------------------------
__global__ __launch_bounds__(256) void prep_weights(
    const float* __restrict__ Wq, const float* __restrict__ Woff,
    const float* __restrict__ Wa, const float* __restrict__ Wk,
    const float* __restrict__ Wv, const float* __restrict__ Wo,
    const float* __restrict__ bq, const float* __restrict__ boff,
    const float* __restrict__ ba, const float* __restrict__ bk,
    const float* __restrict__ bv,
    const float* __restrict__ q_in, const float* __restrict__ kv_in,
    u16* __restrict__ Wcat1, u16* __restrict__ Wcat2, u16* __restrict__ Wob,
    float* __restrict__ bcat1, float* __restrict__ bcat2,
    u16* __restrict__ q_bf, u16* __restrict__ kv_bf, int n8)
{
    const int W4  = 65536;   // 512*512/4
    const int W4s = 4096;    // 32*512/4
    const int WEND = 4 * W4 + 2 * W4s;   // 270336
    const int BEND = WEND + 2048;        // bias section (padded)
    int tid = blockIdx.x * 256 + threadIdx.x;
    if (tid < WEND) {
        const float* src; u16* dst; int off;
        int t = tid;
        if (t < W4)                    { src = Wq;    dst = Wcat1;           off = t; }
        else if ((t -= W4) < W4s)      { src = Woff;  dst = Wcat1 + 262144;  off = t; }
        else if ((t -= W4s) < W4s)     { src = Wa;    dst = Wcat1 + 278528;  off = t; }
        else if ((t -= W4s) < W4)      { src = Wk;    dst = Wcat2;           off = t; }
        else if ((t -= W4) < W4)       { src = Wv;    dst = Wcat2 + 262144;  off = t; }
        else                           { src = Wo;    dst = Wob;             off = t - W4; }
        float4 v = ((const float4*)src)[off];
        ushort4 o;
        o.x = f2b(v.x); o.y = f2b(v.y); o.z = f2b(v.z); o.w = f2b(v.w);
        ((ushort4*)dst)[off] = o;
    } else if (tid < BEND) {
        int j = tid - WEND;
        if (j < 576) {
            bcat1[j] = (j < 512) ? bq[j] : (j < 544 ? boff[j - 512] : ba[j - 544]);
        } else if (j < 1600) {
            int j2 = j - 576;
            bcat2[j2] = (j2 < 512) ? bk[j2] : bv[j2 - 512];
        }
    } else {
        int t = tid - BEND;              // 0 .. 2*n8-1, each handles 8 floats
        if (t < 2 * n8) {
            const float* src; u16* dst; int off;
            if (t < n8) { src = q_in;  dst = q_bf;  off = t; }
            else        { src = kv_in; dst = kv_bf; off = t - n8; }
            float4 a = ((const float4*)src)[off * 2];
            float4 b = ((const float4*)src)[off * 2 + 1];
            uint4 w;
            w.x = pk2(a.x, a.y); w.y = pk2(a.z, a.w);
            w.z = pk2(b.x, b.y); w.w = pk2(b.z, b.w);
            ((uint4*)dst)[off] = w;
        }
    }
}

// ---------------------------------------------------------------------------
// Banded deformable attention. One wave per (b, h, 16-query block).
// k|v fused buffer: row stride 1024, k at cols 0..511, v at 512..1023.
// The 4 waves of a block are fully LDS-independent (per-wave sVt/sS/sW
// slices), so block-wide __syncthreads is replaced by wave-local
// s_waitcnt lgkmcnt(0): a wave's own DS writes are complete before its
// subsequent reads; no cross-wave rendezvous.
// ---------------------------------------------------------------------------
#define WAVE_SYNC() do {                                      \
    asm volatile("s_waitcnt lgkmcnt(0)" ::: "memory");        \
    __builtin_amdgcn_sched_barrier(0); } while (0)

__global__ __launch_bounds__(256) void deform_attn_band(
    const u16* __restrict__ q, const u16* __restrict__ kv,
    const float* __restrict__ offlog, u16* __restrict__ out, int B, int L)
{
    __shared__ u16  sVt[4][64 * 40];
    __shared__ float sS[4][16 * 36];
    __shared__ float sW[4][16 * 36];

    const int wave = threadIdx.x >> 6;
    const int lane = threadIdx.x & 63;
    const int gw = blockIdx.x * 4 + wave;     // over B*NH*(L/16)
    const int nlb = L >> 4;
    const int lblk = gw % nlb;
    const int bh = gw / nlb;
    const int h = bh % NH;
    const int b = bh / NH;
    const int l0 = lblk << 4;

    u16*  __restrict__ vt = sVt[wave];
    float* __restrict__ Ss = sS[wave];
    float* __restrict__ Ws = sW[wave];

    const size_t brow = (size_t)b * L;
    const int headoff = h * DD;

    const int l_loc = lane >> 2, p = lane & 3;
    const size_t obase = (brow + l0 + l_loc) * 64 + h * 4 + p;
    const float offv  = offlog[obase];
    const float logit = offlog[obase + 32];

    const int fr = lane & 15, kg = lane >> 4;

    const u16* qrow = q + (brow + l0 + fr) * DM + headoff;
    frag_ab qf0 = *(const frag_ab*)(qrow + kg * 8);
    frag_ab qf1 = *(const frag_ab*)(qrow + kg * 8 + 32);

    frag_ab kf[2][2];
#pragma unroll
    for (int jf = 0; jf < 2; ++jf) {
        int rr = l0 - 8 + jf * 16 + fr;
        rr = min(max(rr, 0), L - 1);
        const u16* krow = kv + (brow + rr) * 1024 + headoff;
        kf[jf][0] = *(const frag_ab*)(krow + kg * 8);
        kf[jf][1] = *(const frag_ab*)(krow + kg * 8 + 32);
    }

    const int vr = lane & 31, vd0 = (lane >> 5) * 32;
    int vrr = min(max(l0 - 8 + vr, 0), L - 1);
    const u16* vrow = kv + (brow + vrr) * 1024 + 512 + headoff + vd0;
    frag_ab vl[4];
#pragma unroll
    for (int i = 0; i < 4; ++i)
        vl[i] = *(const frag_ab*)(vrow + i * 8);

    f32x4 accS[2] = {};
#pragma unroll
    for (int jf = 0; jf < 2; ++jf) {
        accS[jf] = __builtin_amdgcn_mfma_f32_16x16x32_bf16(qf0, kf[jf][0], accS[jf], 0, 0, 0);
        accS[jf] = __builtin_amdgcn_mfma_f32_16x16x32_bf16(qf1, kf[jf][1], accS[jf], 0, 0, 0);
    }

#pragma unroll
    for (int i = 0; i < 4; ++i)
#pragma unroll
        for (int j = 0; j < 8; ++j)
            vt[(vd0 + i * 8 + j) * 40 + vr] = (u16)vl[i][j];

#pragma unroll
    for (int jf = 0; jf < 2; ++jf)
#pragma unroll
        for (int r = 0; r < 4; ++r)
            Ss[(kg * 4 + r) * 36 + jf * 16 + fr] = accS[jf][r];

#pragma unroll
    for (int i = 0; i < 9; ++i)
        Ws[lane + 64 * i] = 0.f;

    WAVE_SYNC();

    float pos = fminf(fmaxf((float)(l0 + l_loc) + offv, 0.f), (float)(L - 1));
    float ff = floorf(pos);
    int i0 = (int)ff;
    float fw = pos - ff;
    int c0 = i0 - (l0 - 8);
    c0 = min(max(c0, 0), 30);
    float S0 = Ss[l_loc * 36 + c0];
    float S1 = Ss[l_loc * 36 + c0 + 1];
    float t = (S0 + fw * (S1 - S0)) * 0.125f + logit;
    float m1 = fmaxf(t, __shfl_xor(t, 1));
    float mx = fmaxf(m1, __shfl_xor(m1, 2));
    float e = __expf(t - mx);
    float s1 = e + __shfl_xor(e, 1);
    float ssum = s1 + __shfl_xor(s1, 2);
    float wgt = e * __builtin_amdgcn_rcpf(ssum);
    atomicAdd(&Ws[l_loc * 36 + c0], (1.f - fw) * wgt);
    atomicAdd(&Ws[l_loc * 36 + c0 + 1], fw * wgt);

    WAVE_SYNC();

    float4 w0 = *(const float4*)&Ws[fr * 36 + kg * 8];
    float4 w1 = *(const float4*)&Ws[fr * 36 + kg * 8 + 4];
    frag_ab wf;
    wf[0] = (short)f2b(w0.x); wf[1] = (short)f2b(w0.y);
    wf[2] = (short)f2b(w0.z); wf[3] = (short)f2b(w0.w);
    wf[4] = (short)f2b(w1.x); wf[5] = (short)f2b(w1.y);
    wf[6] = (short)f2b(w1.z); wf[7] = (short)f2b(w1.w);

#pragma unroll
    for (int md = 0; md < 4; ++md) {
        frag_ab af = *(const frag_ab*)&vt[(md * 16 + fr) * 40 + kg * 8];
        f32x4 o = {};
        o = __builtin_amdgcn_mfma_f32_16x16x32_bf16(af, wf, o, 0, 0, 0);
        ushort4 pk;
        pk.x = f2b(o[0]); pk.y = f2b(o[1]); pk.z = f2b(o[2]); pk.w = f2b(o[3]);
        *(ushort4*)&out[(brow + l0 + fr) * DM + headoff + md * 16 + kg * 4] = pk;
    }
}

// ---------------------------------------------------------------------------
extern "C" void kernel_launch(void* const* d_in, const int* in_sizes, int n_in,
                              void* d_out, int out_size, void* d_ws, size_t ws_size,
                              hipStream_t stream) {
    const float* q_in  = (const float*)d_in[0];
    const float* kv_in = (const float*)d_in[1];
    const float* Wq = (const float*)d_in[2];  const float* bq = (const float*)d_in[3];
    const float* Wk = (const float*)d_in[4];  const float* bk = (const float*)d_in[5];
    const float* Wv = (const float*)d_in[6];  const float* bv = (const float*)d_in[7];
    const float* Woff=(const float*)d_in[8];  const float* boff=(const float*)d_in[9];
    const float* Wa = (const float*)d_in[10]; const float* ba = (const float*)d_in[11];
    const float* Wo = (const float*)d_in[12]; const float* bo = (const float*)d_in[13];

    const int M = in_sizes[0] / DM;     // B*L = 16384
    const int L = 4096;
    const int B = M / L;

    char* p = (char*)d_ws;
    u16* attn_o = (u16*)p;               p += (size_t)M * DM * 2;     // attention output
    u16* Wcat1  = (u16*)p;               p += (size_t)768 * DM * 2;   // 640 used; pad for OOB staging
    u16* Wcat2  = (u16*)p;               p += (size_t)1024 * DM * 2;
    u16* Wob    = (u16*)p;               p += (size_t)DM * DM * 2;
    float* bcat1= (float*)p;             p += 640 * 4;
    float* bcat2= (float*)p;             p += 1024 * 4;
    u16* q_ws   = (u16*)p;               p += (size_t)M * DM * 2;
    u16* kv_ws  = (u16*)p;               p += (size_t)M * 1024 * 2;   // k|v fused
    float* offlog = (float*)p;           p += (size_t)M * 64 * 4;

    // bf16 input casts — alias dead regions (same-stream serialization):
    //   q_bf  lives prep->proj; attn_o is only written later by deform_attn_band
    //   kv_bf lives prep->proj; d_out is only written later by out_gemm (fully)
    u16* q_bf  = attn_o;
    u16* kv_bf = (u16*)d_out;

    const int n8 = M * DM / 8;          // 8 floats per cast thread
    const int prep_threads = 4 * 65536 + 2 * 4096 + 2048 + 2 * n8;
    hipLaunchKernelGGL(prep_weights, dim3((prep_threads + 255) / 256), dim3(256), 0, stream,
                       Wq, Woff, Wa, Wk, Wv, Wo, bq, boff, ba, bk, bv,
                       q_in, kv_in,
                       Wcat1, Wcat2, Wob, bcat1, bcat2, q_bf, kv_bf, n8);

    // merged projections (all-bf16 async staging, 8-wave blocks):
    //   y<5 -> q/off/a, y>=5 -> k|v
    hipLaunchKernelGGL(proj_gemm, dim3(M / 128, 13), dim3(512), 0, stream,
                       q_bf, kv_bf, Wcat1, Wcat2, bcat1, bcat2,
                       q_ws, offlog, kv_ws);

    // banded attention: 1 wave per (b,h,16 queries)
    int nwaves = B * NH * (L / 16);
    hipLaunchKernelGGL(deform_attn_band, dim3(nwaves / 4), dim3(256), 0, stream,
                       q_ws, kv_ws, offlog, attn_o, B, L);

    // output projection -> fp32 d_out
    hipLaunchKernelGGL(out_gemm, dim3(M / 128, 4), dim3(512), 0, stream,
                       attn_o, Wob, bo, (float*)d_out);
}